// Round 8
// baseline (608.196 us; speedup 1.0000x reference)
//
#include <hip/hip_runtime.h>
#include <stdint.h>

// B=8192, N=17, C=512, H=8, HD=64 — f16 pipeline (inputs fp32)
// Fused qkv-GEMM (head-grouped W) + MFMA attention epilogue.
// GEMM loops: BK=32, 4 LDS buffers, counted vmcnt (T3/T4), 1 barrier/K-tile.

typedef __attribute__((ext_vector_type(4))) float f32x4;
typedef _Float16 f16x8 __attribute__((ext_vector_type(8)));
typedef _Float16 f16x4 __attribute__((ext_vector_type(4)));
typedef _Float16 f16x2 __attribute__((ext_vector_type(2)));

__device__ __forceinline__ unsigned short f2h(float f) {
  return __builtin_bit_cast(unsigned short, (_Float16)f);
}
__device__ __forceinline__ float h2f(unsigned short h) {
  return (float)__builtin_bit_cast(_Float16, h);
}
__device__ __forceinline__ float fdot2u(uint32_t a, uint32_t b, float c) {
  return __builtin_amdgcn_fdot2(__builtin_bit_cast(f16x2, a),
                                __builtin_bit_cast(f16x2, b), c, false);
}

#define GLOAD_LDS16(gptr, lptr)                                          \
  __builtin_amdgcn_global_load_lds(                                      \
      (__attribute__((address_space(1))) void*)(gptr),                   \
      (__attribute__((address_space(3))) void*)(lptr), 16, 0, 0)

#define VMCNT(n) asm volatile("s_waitcnt vmcnt(" #n ")" ::: "memory")

__device__ __forceinline__ f32x4 mfma16(f16x8 a, f16x8 b, f32x4 c) {
  return __builtin_amdgcn_mfma_f32_16x16x32_f16(a, b, c, 0, 0, 0);
}
__device__ __forceinline__ f32x4 mfma16k16(f16x4 a, f16x4 b, f32x4 c) {
  return __builtin_amdgcn_mfma_f32_16x16x16f16(a, b, c, 0, 0, 0);
}

// ---------------- cast fp32 -> f16, 4 elems/thread ----------------
__global__ __launch_bounds__(256) void k_cvt(const float* __restrict__ in,
                                             unsigned short* __restrict__ out,
                                             long n4) {
  long i = (long)blockIdx.x * 256 + threadIdx.x;
  if (i >= n4) return;
  float4 a = reinterpret_cast<const float4*>(in)[i];
  ushort4 o;
  o.x = f2h(a.x); o.y = f2h(a.y); o.z = f2h(a.z); o.w = f2h(a.w);
  reinterpret_cast<ushort4*>(out)[i] = o;
}

// ---- transpose-cast W[K][Norig] fp32 -> Wt[N][K] f16; PERM = head-group ----
template <bool PERM>
__global__ __launch_bounds__(256) void k_cvt_t(const float* __restrict__ W,
                                               unsigned short* __restrict__ Wt,
                                               int K, int Norig) {
  int i = blockIdx.x * 256 + threadIdx.x;
  if (i >= K * Norig) return;
  int np = i / K, k = i - np * K;
  int n = np;
  if (PERM) {
    int h = np / 192, rem = np - h * 192;
    int t = rem >> 6, d = rem & 63;
    n = t * 512 + h * 64 + d;
  }
  Wt[i] = f2h(W[(size_t)k * Norig + n]);
}

// ---- permute bias: bqp[n'] = b[n] ----
__global__ __launch_bounds__(256) void k_permb(const float* __restrict__ b,
                                               float* __restrict__ bqp) {
  int np = blockIdx.x * 256 + threadIdx.x;
  if (np >= 1536) return;
  int h = np / 192, rem = np - h * 192;
  int t = rem >> 6, d = rem & 63;
  bqp[np] = b[t * 512 + h * 64 + d];
}

// ============ fused qkv-GEMM + MFMA attention ============
// BM=128 (7 batches), BN=192 (one head q|k|v), BK=32, KT=16,
// 512 thr = 8 waves (2M x 4N), per-wave 64x48 (4x3 frags of 16x16x32).
// LDS: 4 buffers x (A 128x32 + B 192x32) f16 = 4 x 20,480 B = 81,920 B.
// Counted vmcnt: wave stages c={3 (w<4), 2} slabs/tile; steady wait = 2c.
// Epilogue overlay (shorts): SQ[128][136]@0, VT[8][64][24]@17408,
// PL[8][16][24]@29696, SE[8][34]f32@32768 — end 33,312 shorts.
__global__ __launch_bounds__(512, 4) void k_fused(
    const unsigned short* __restrict__ A,   // xb  [139264][512] f16
    const unsigned short* __restrict__ Bt,  // wqt'[1536][512] f16
    const float* __restrict__ bqp,          // permuted bias [1536]
    const float* __restrict__ outer,        // [8][17][17]
    const float* __restrict__ alpha_p,      // [1]
    unsigned short* __restrict__ ao) {      // [139264][512] f16
  __shared__ __align__(16) unsigned short smem[40960];  // 81,920 B

  const int tid = threadIdx.x;
  const int w = tid >> 6, lane = tid & 63;
  const int wm = w >> 2, wn = w & 3;
  const int lr = lane & 15, lk = lane >> 4;

  // bijective XCD swizzle (grid = 1171*8); h inner keeps A-panel sharers
  // in one XCD chunk.
  const int bid = (blockIdx.x & 7) * ((int)gridDim.x >> 3) + (blockIdx.x >> 3);
  const int mt = bid >> 3, h = bid & 7;
  const int batch0 = mt * 7;
  const int brow = batch0 * 17;
  const int bcol = h * 192;

  // staging: slab = 16 rows x 32 cols (1 KB). lane l -> row l>>2, granule l&3.
  // swizzle: src granule = g ^ ((row>>1)&3); read granule = lk ^ ((lr>>1)&3).
  const int rsl = lane >> 2;
  const int swcol = ((lane & 3) ^ ((lane >> 3) & 3)) << 3;  // f16 units
  const bool cw3 = (w < 4);

  f32x4 acc[4][3];
#pragma unroll
  for (int m = 0; m < 4; m++)
#pragma unroll
    for (int n = 0; n < 3; n++) acc[m][n] = f32x4{0.f, 0.f, 0.f, 0.f};

  auto STAGE1 = [&](int t, int s) {
    unsigned short* dst = smem + (t & 3) * 10240 + s * 512;  // wave-uniform
    const unsigned short* src;
    if (s < 8) {  // A slabs: rows 0..127
      int gr = brow + s * 16 + rsl;
      if (gr > 139263) gr = 139263;  // clamp last row-tile (junk rows unused)
      src = A + (size_t)gr * 512 + t * 32 + swcol;
    } else {  // B slabs: rows 0..191
      src = Bt + (size_t)(bcol + (s - 8) * 16 + rsl) * 512 + t * 32 + swcol;
    }
    GLOAD_LDS16(src, dst);
  };
  auto STAGE = [&](int t) {
    STAGE1(t, w);
    STAGE1(t, w + 8);
    if (cw3) STAGE1(t, w + 16);
  };

  // prologue: 3 tiles in flight, wait tile 0 (allow 2c outstanding)
  STAGE(0); STAGE(1); STAGE(2);
  if (cw3) { VMCNT(6); } else { VMCNT(4); }
  __builtin_amdgcn_s_barrier();

  const int gx = (lk ^ ((lr >> 1) & 3)) << 3;
  for (int t = 0; t < 16; ++t) {
    if (t + 3 < 16) STAGE(t + 3);
    const unsigned short* bufp = smem + (t & 3) * 10240;
    const unsigned short* sa = bufp + (wm * 64 + lr) * 32 + gx;
    const unsigned short* sb = bufp + 4096 + (wn * 48 + lr) * 32 + gx;
    f16x8 a0 = *(const f16x8*)(sa);
    f16x8 a1 = *(const f16x8*)(sa + 512);
    f16x8 a2 = *(const f16x8*)(sa + 1024);
    f16x8 a3 = *(const f16x8*)(sa + 1536);
    f16x8 b0 = *(const f16x8*)(sb);
    f16x8 b1 = *(const f16x8*)(sb + 512);
    f16x8 b2 = *(const f16x8*)(sb + 1024);
    acc[0][0] = mfma16(a0, b0, acc[0][0]);
    acc[0][1] = mfma16(a0, b1, acc[0][1]);
    acc[0][2] = mfma16(a0, b2, acc[0][2]);
    acc[1][0] = mfma16(a1, b0, acc[1][0]);
    acc[1][1] = mfma16(a1, b1, acc[1][1]);
    acc[1][2] = mfma16(a1, b2, acc[1][2]);
    acc[2][0] = mfma16(a2, b0, acc[2][0]);
    acc[2][1] = mfma16(a2, b1, acc[2][1]);
    acc[2][2] = mfma16(a2, b2, acc[2][2]);
    acc[3][0] = mfma16(a3, b0, acc[3][0]);
    acc[3][1] = mfma16(a3, b1, acc[3][1]);
    acc[3][2] = mfma16(a3, b2, acc[3][2]);
    // counted wait: tile t+1 must be resident at the barrier
    if (t < 13) {
      if (cw3) { VMCNT(6); } else { VMCNT(4); }
    } else if (t == 13) {
      if (cw3) { VMCNT(3); } else { VMCNT(2); }
    } else if (t == 14) {
      VMCNT(0);
    }
    __builtin_amdgcn_s_barrier();
  }

  // ---- epilogue overlay ----
  unsigned short* SQ = smem;                 // [128][136] q|k
  unsigned short* VT = smem + 17408;         // [7(8)][64][24] v^T (tl 0..16)
  unsigned short* PL = smem + 29696;         // [8][16][24] P f16
  float* SE = (float*)(smem + 32768);        // [8][34] edge logits

  // epi-1: acc(+bias) -> scratch
  {
    const int er0 = wm * 64 + (lane >> 4) * 4;
    const int ec0 = wn * 48 + lr;
#pragma unroll
    for (int nf = 0; nf < 3; ++nf) {
      const int col = ec0 + nf * 16;
      const float bv = bqp[bcol + col];
#pragma unroll
      for (int mf = 0; mf < 4; ++mf) {
        const int t0 = er0 + mf * 16;
        float v0 = acc[mf][nf][0] + bv, v1 = acc[mf][nf][1] + bv;
        float v2 = acc[mf][nf][2] + bv, v3 = acc[mf][nf][3] + bv;
        if (col < 128) {
          SQ[(t0 + 0) * 136 + col] = f2h(v0);
          SQ[(t0 + 1) * 136 + col] = f2h(v1);
          SQ[(t0 + 2) * 136 + col] = f2h(v2);
          SQ[(t0 + 3) * 136 + col] = f2h(v3);
        } else {
          const int d = col - 128;
#pragma unroll
          for (int rr = 0; rr < 4; ++rr) {
            const int tt = t0 + rr;
            const int bb = tt / 17, tl = tt - bb * 17;
            float vv = (rr == 0 ? v0 : rr == 1 ? v1 : rr == 2 ? v2 : v3);
            if (bb < 7) VT[bb * 1536 + d * 24 + tl] = f2h(vv);
          }
        }
      }
    }
  }
  __syncthreads();

  // epi-2: per-wave MFMA attention, batch = w
  const int nb = min(7, 8192 - batch0);
  if (w < nb) {
    const float alpha = alpha_p[0];
    const int base = w * 17;
    unsigned short* PLw = PL + w * 384;
    unsigned short* VTw = VT + w * 1536;
    float* SEw = SE + w * 34;

    // logits main 16x16, K=64 via 2 MFMA (A=q rows, B=k rows -> q.k^T)
    f32x4 sAcc = f32x4{0.f, 0.f, 0.f, 0.f};
#pragma unroll
    for (int kk = 0; kk < 2; ++kk) {
      f16x8 qa = *(const f16x8*)(SQ + (base + lr) * 136 + kk * 32 + lk * 8);
      f16x8 kb = *(const f16x8*)(SQ + (base + lr) * 136 + 64 + kk * 32 + lk * 8);
      sAcc = mfma16(qa, kb, sAcc);
    }

    // edge dots: lanes 0..15 -> (r,16); lanes 16..32 -> (16,m)
    if (lane < 33) {
      const int r_ = (lane < 16) ? lane : 16;
      const int m_ = (lane < 16) ? 16 : lane - 16;
      const uint4* qr = (const uint4*)(SQ + (base + r_) * 136);
      const uint4* kr = (const uint4*)(SQ + (base + m_) * 136 + 64);
      float dt = 0.f;
#pragma unroll
      for (int c = 0; c < 8; ++c) {
        uint4 qa = qr[c], ka = kr[c];
        dt = fdot2u(qa.x, ka.x, dt);
        dt = fdot2u(qa.y, ka.y, dt);
        dt = fdot2u(qa.z, ka.z, dt);
        dt = fdot2u(qa.w, ka.w, dt);
      }
      float sv = (dt + alpha * outer[h * 289 + r_ * 17 + m_]) * 0.125f;
      SEw[(lane < 16) ? lane : (17 + m_)] = sv;
    }
    __builtin_amdgcn_wave_barrier();
    asm volatile("" ::: "memory");

    // softmax on C-layout: col=m=lr, rows g4+j
    const int g4 = (lane >> 4) * 4;
    float sp[4], rmax[4], p[4], pe[4], rsum[4], inv[4];
#pragma unroll
    for (int j = 0; j < 4; ++j) {
      sp[j] = (sAcc[j] + alpha * outer[h * 289 + (g4 + j) * 17 + lr]) * 0.125f;
      rmax[j] = sp[j];
    }
#pragma unroll
    for (int d = 1; d < 16; d <<= 1)
#pragma unroll
      for (int j = 0; j < 4; ++j)
        rmax[j] = fmaxf(rmax[j], __shfl_xor(rmax[j], d));
#pragma unroll
    for (int j = 0; j < 4; ++j) {
      float ec = SEw[g4 + j];           // S[row][16]
      rmax[j] = fmaxf(rmax[j], ec);
      p[j] = __expf(sp[j] - rmax[j]);
      pe[j] = __expf(ec - rmax[j]);
      rsum[j] = p[j];
    }
#pragma unroll
    for (int d = 1; d < 16; d <<= 1)
#pragma unroll
      for (int j = 0; j < 4; ++j) rsum[j] += __shfl_xor(rsum[j], d);
#pragma unroll
    for (int j = 0; j < 4; ++j) {
      rsum[j] += pe[j];
      inv[j] = 1.f / rsum[j];
      PLw[(g4 + j) * 24 + lr] = f2h(p[j]);
    }
    __builtin_amdgcn_wave_barrier();
    asm volatile("" ::: "memory");

    // PV: 4x mfma 16x16x16 (tokens 0..15) + in-register rank-1 for token 16
    f16x4 pa = *(const f16x4*)(PLw + lr * 24 + lk * 4);
    f32x4 o[4];
    float v16[4];
#pragma unroll
    for (int nf = 0; nf < 4; ++nf) {
      f16x4 vb = *(const f16x4*)(VTw + (nf * 16 + lr) * 24 + lk * 4);
      o[nf] = mfma16k16(pa, vb, f32x4{0.f, 0.f, 0.f, 0.f});
      v16[nf] = h2f(VTw[(nf * 16 + lr) * 24 + 16]);
    }
    const size_t gr0 = (size_t)(brow + base) * 512 + h * 64;
#pragma unroll
    for (int nf = 0; nf < 4; ++nf)
#pragma unroll
      for (int j = 0; j < 4; ++j)
        ao[gr0 + (size_t)(g4 + j) * 512 + nf * 16 + lr] =
            f2h((o[nf][j] + pe[j] * v16[nf]) * inv[j]);

    // row 16: VALU (lane = d)
    {
      float mx16 = -1e30f;
#pragma unroll 1
      for (int m = 0; m < 17; ++m) mx16 = fmaxf(mx16, SEw[17 + m]);
      float o16 = 0.f, s16 = 0.f;
#pragma unroll 1
      for (int m = 0; m < 17; ++m) {
        float pm = __expf(SEw[17 + m] - mx16);
        s16 += pm;
        o16 += pm * h2f(VTw[lane * 24 + m]);
      }
      ao[gr0 + (size_t)16 * 512 + lane] = f2h(o16 / s16);
    }
  }
}

// ============ proj GEMM: 128x128, BK=32, 4 buffers, counted vmcnt ========
__global__ __launch_bounds__(512, 4) void k_proj(
    const unsigned short* __restrict__ A,   // ao [139264][512] f16
    const unsigned short* __restrict__ Bt,  // wpt [512][512] f16
    const float* __restrict__ bias,         // [512]
    float* __restrict__ C) {                // [139264][512] fp32
  __shared__ __align__(16) unsigned short smem[32768];  // 65,536 B

  const int tid = threadIdx.x;
  const int w = tid >> 6, lane = tid & 63;
  const int wm = w >> 2, wn = w & 3;
  const int lr = lane & 15, lk = lane >> 4;

  const int bid = (blockIdx.x & 7) * ((int)gridDim.x >> 3) + (blockIdx.x >> 3);
  const int brow = (bid >> 2) << 7;
  const int bcol = (bid & 3) << 7;

  const int rsl = lane >> 2;
  const int swcol = ((lane & 3) ^ ((lane >> 3) & 3)) << 3;

  f32x4 acc[4][2];
#pragma unroll
  for (int m = 0; m < 4; m++)
#pragma unroll
    for (int n = 0; n < 2; n++) acc[m][n] = f32x4{0.f, 0.f, 0.f, 0.f};

  auto STAGE1 = [&](int t, int s) {
    unsigned short* dst = smem + (t & 3) * 8192 + s * 512;
    const unsigned short* src =
        (s < 8) ? A + (size_t)(brow + s * 16 + rsl) * 512 + t * 32 + swcol
                : Bt + (size_t)(bcol + (s - 8) * 16 + rsl) * 512 + t * 32 + swcol;
    GLOAD_LDS16(src, dst);
  };
  auto STAGE = [&](int t) {
    STAGE1(t, w);
    STAGE1(t, w + 8);
  };

  STAGE(0); STAGE(1); STAGE(2);
  VMCNT(4);
  __builtin_amdgcn_s_barrier();

  const int gx = (lk ^ ((lr >> 1) & 3)) << 3;
  for (int t = 0; t < 16; ++t) {
    if (t + 3 < 16) STAGE(t + 3);
    const unsigned short* bufp = smem + (t & 3) * 8192;
    const unsigned short* sa = bufp + (wm * 64 + lr) * 32 + gx;
    const unsigned short* sb = bufp + 4096 + (wn * 32 + lr) * 32 + gx;
    f16x8 a0 = *(const f16x8*)(sa);
    f16x8 a1 = *(const f16x8*)(sa + 512);
    f16x8 a2 = *(const f16x8*)(sa + 1024);
    f16x8 a3 = *(const f16x8*)(sa + 1536);
    f16x8 b0 = *(const f16x8*)(sb);
    f16x8 b1 = *(const f16x8*)(sb + 512);
    acc[0][0] = mfma16(a0, b0, acc[0][0]);
    acc[0][1] = mfma16(a0, b1, acc[0][1]);
    acc[1][0] = mfma16(a1, b0, acc[1][0]);
    acc[1][1] = mfma16(a1, b1, acc[1][1]);
    acc[2][0] = mfma16(a2, b0, acc[2][0]);
    acc[2][1] = mfma16(a2, b1, acc[2][1]);
    acc[3][0] = mfma16(a3, b0, acc[3][0]);
    acc[3][1] = mfma16(a3, b1, acc[3][1]);
    if (t < 13) {
      VMCNT(4);
    } else if (t == 13) {
      VMCNT(2);
    } else if (t == 14) {
      VMCNT(0);
    }
    __builtin_amdgcn_s_barrier();
  }

  const int orow = brow + wm * 64 + (lane >> 4) * 4;
  const int ocol0 = bcol + wn * 32 + lr;
#pragma unroll
  for (int n = 0; n < 2; n++) {
    const int col = ocol0 + n * 16;
    const float bv = bias[col];
#pragma unroll
    for (int m = 0; m < 4; m++) {
      const int row = orow + m * 16;
#pragma unroll
      for (int r = 0; r < 4; r++)
        C[(size_t)(row + r) * 512 + col] = acc[m][n][r] + bv;
    }
  }
}

// ---------------- launch ----------------
extern "C" void kernel_launch(void* const* d_in, const int* in_sizes, int n_in,
                              void* d_out, int out_size, void* d_ws,
                              size_t ws_size, hipStream_t stream) {
  const float* x      = (const float*)d_in[0];
  const float* W_qkv  = (const float*)d_in[1];
  const float* b_qkv  = (const float*)d_in[2];
  const float* outer  = (const float*)d_in[3];
  const float* alpha  = (const float*)d_in[4];
  const float* W_proj = (const float*)d_in[5];
  const float* b_proj = (const float*)d_in[6];

  char* ws = (char*)d_ws;
  unsigned short* xb  = (unsigned short*)(ws);              // 142,606,336 B
  unsigned short* ao  = (unsigned short*)(ws + 142606336);  // 142,606,336 B
  unsigned short* wqt = (unsigned short*)(ws + 285212672);  // 1,572,864 B
  unsigned short* wpt = (unsigned short*)(ws + 286785536);  // 524,288 B
  float*          bqp = (float*)(ws + 287309824);           // 6,144 B

  k_cvt<<<dim3(69632), dim3(256), 0, stream>>>(x, xb, 17825792L);
  k_cvt_t<true><<<dim3(3072), dim3(256), 0, stream>>>(W_qkv, wqt, 512, 1536);
  k_cvt_t<false><<<dim3(1024), dim3(256), 0, stream>>>(W_proj, wpt, 512, 512);
  k_permb<<<dim3(6), dim3(256), 0, stream>>>(b_qkv, bqp);

  // fused qkv-GEMM + attention: 1171 row-tiles (7 batches each) x 8 heads
  k_fused<<<dim3(9368), dim3(512), 0, stream>>>(xb, wqt, bqp, outer, alpha, ao);

  // proj GEMM: 1088 row-tiles x 4 col-tiles
  k_proj<<<dim3(4352), dim3(512), 0, stream>>>(ao, wpt, b_proj, (float*)d_out);
}

// Round 9
// 607.390 us; speedup vs baseline: 1.0013x; 1.0013x over previous
//
#include <hip/hip_runtime.h>
#include <stdint.h>

// B=8192, N=17, C=512, H=8, HD=64 — f16 pipeline (inputs fp32)
// Fused qkv-GEMM (head-grouped W) + MFMA attention epilogue.
// GEMM loops: BK=32, 4 LDS buffers, counted vmcnt (T3/T4), 1 barrier/K-tile.

typedef __attribute__((ext_vector_type(4))) float f32x4;
typedef _Float16 f16x8 __attribute__((ext_vector_type(8)));
typedef _Float16 f16x4 __attribute__((ext_vector_type(4)));
typedef _Float16 f16x2 __attribute__((ext_vector_type(2)));

__device__ __forceinline__ unsigned short f2h(float f) {
  return __builtin_bit_cast(unsigned short, (_Float16)f);
}
__device__ __forceinline__ float h2f(unsigned short h) {
  return (float)__builtin_bit_cast(_Float16, h);
}
__device__ __forceinline__ float fdot2u(uint32_t a, uint32_t b, float c) {
  return __builtin_amdgcn_fdot2(__builtin_bit_cast(f16x2, a),
                                __builtin_bit_cast(f16x2, b), c, false);
}

#define GLOAD_LDS16(gptr, lptr)                                          \
  __builtin_amdgcn_global_load_lds(                                      \
      (__attribute__((address_space(1))) void*)(gptr),                   \
      (__attribute__((address_space(3))) void*)(lptr), 16, 0, 0)

#define VMCNT(n) asm volatile("s_waitcnt vmcnt(" #n ")" ::: "memory")

__device__ __forceinline__ f32x4 mfma16(f16x8 a, f16x8 b, f32x4 c) {
  return __builtin_amdgcn_mfma_f32_16x16x32_f16(a, b, c, 0, 0, 0);
}
__device__ __forceinline__ f32x4 mfma16k16(f16x4 a, f16x4 b, f32x4 c) {
  return __builtin_amdgcn_mfma_f32_16x16x16f16(a, b, c, 0, 0, 0);
}

// ---------------- cast fp32 -> f16, 4 elems/thread ----------------
__global__ __launch_bounds__(256) void k_cvt(const float* __restrict__ in,
                                             unsigned short* __restrict__ out,
                                             long n4) {
  long i = (long)blockIdx.x * 256 + threadIdx.x;
  if (i >= n4) return;
  float4 a = reinterpret_cast<const float4*>(in)[i];
  ushort4 o;
  o.x = f2h(a.x); o.y = f2h(a.y); o.z = f2h(a.z); o.w = f2h(a.w);
  reinterpret_cast<ushort4*>(out)[i] = o;
}

// ---- transpose-cast W[K][Norig] fp32 -> Wt[N][K] f16; PERM = head-group ----
template <bool PERM>
__global__ __launch_bounds__(256) void k_cvt_t(const float* __restrict__ W,
                                               unsigned short* __restrict__ Wt,
                                               int K, int Norig) {
  int i = blockIdx.x * 256 + threadIdx.x;
  if (i >= K * Norig) return;
  int np = i / K, k = i - np * K;
  int n = np;
  if (PERM) {
    int h = np / 192, rem = np - h * 192;
    int t = rem >> 6, d = rem & 63;
    n = t * 512 + h * 64 + d;
  }
  Wt[i] = f2h(W[(size_t)k * Norig + n]);
}

// ---- permute bias: bqp[n'] = b[n] ----
__global__ __launch_bounds__(256) void k_permb(const float* __restrict__ b,
                                               float* __restrict__ bqp) {
  int np = blockIdx.x * 256 + threadIdx.x;
  if (np >= 1536) return;
  int h = np / 192, rem = np - h * 192;
  int t = rem >> 6, d = rem & 63;
  bqp[np] = b[t * 512 + h * 64 + d];
}

// ============ fused qkv-GEMM + MFMA attention ============
// BM=128 (7 batches), BN=192 (one head q|k|v), BK=32, KT=16,
// 512 thr = 8 waves (2M x 4N), per-wave 64x48 (4x3 frags of 16x16x32).
// LDS: 4 buffers x (A 128x32 + B 192x32) f16 = 4 x 20,480 B = 81,920 B.
// Counted vmcnt: wave stages c={3 (w<4), 2} slabs/tile; steady wait = 2c.
// Epilogue overlay (shorts): SQ[128][136]@0, VT[8][64][24]@17408,
// PL[8][16][24]@29696, SE[8][34]f32@32768 — end 33,312 shorts.
__global__ __launch_bounds__(512, 4) void k_fused(
    const unsigned short* __restrict__ A,   // xb  [139264][512] f16
    const unsigned short* __restrict__ Bt,  // wqt'[1536][512] f16
    const float* __restrict__ bqp,          // permuted bias [1536]
    const float* __restrict__ outer,        // [8][17][17]
    const float* __restrict__ alpha_p,      // [1]
    unsigned short* __restrict__ ao) {      // [139264][512] f16
  __shared__ __align__(16) unsigned short smem[40960];  // 81,920 B

  const int tid = threadIdx.x;
  const int w = tid >> 6, lane = tid & 63;
  const int wm = w >> 2, wn = w & 3;
  const int lr = lane & 15, lk = lane >> 4;

  // bijective XCD swizzle (grid = 1171*8); h inner keeps A-panel sharers
  // in one XCD chunk.
  const int bid = (blockIdx.x & 7) * ((int)gridDim.x >> 3) + (blockIdx.x >> 3);
  const int mt = bid >> 3, h = bid & 7;
  const int batch0 = mt * 7;
  const int brow = batch0 * 17;
  const int bcol = h * 192;

  // staging: slab = 16 rows x 32 cols (1 KB). lane l -> row l>>2, granule l&3.
  // swizzle: src granule = g ^ ((row>>1)&3); read granule = lk ^ ((lr>>1)&3).
  const int rsl = lane >> 2;
  const int swcol = ((lane & 3) ^ ((lane >> 3) & 3)) << 3;  // f16 units
  const bool cw3 = (w < 4);

  f32x4 acc[4][3];
#pragma unroll
  for (int m = 0; m < 4; m++)
#pragma unroll
    for (int n = 0; n < 3; n++) acc[m][n] = f32x4{0.f, 0.f, 0.f, 0.f};

  auto STAGE1 = [&](int t, int s) {
    unsigned short* dst = smem + (t & 3) * 10240 + s * 512;  // wave-uniform
    const unsigned short* src;
    if (s < 8) {  // A slabs: rows 0..127
      int gr = brow + s * 16 + rsl;
      if (gr > 139263) gr = 139263;  // clamp last row-tile (junk rows unused)
      src = A + (size_t)gr * 512 + t * 32 + swcol;
    } else {  // B slabs: rows 0..191
      src = Bt + (size_t)(bcol + (s - 8) * 16 + rsl) * 512 + t * 32 + swcol;
    }
    GLOAD_LDS16(src, dst);
  };
  auto STAGE = [&](int t) {
    STAGE1(t, w);
    STAGE1(t, w + 8);
    if (cw3) STAGE1(t, w + 16);
  };

  // prologue: 3 tiles in flight, wait tile 0 (allow 2c outstanding)
  STAGE(0); STAGE(1); STAGE(2);
  if (cw3) { VMCNT(6); } else { VMCNT(4); }
  __builtin_amdgcn_s_barrier();

  const int gx = (lk ^ ((lr >> 1) & 3)) << 3;
  for (int t = 0; t < 16; ++t) {
    if (t + 3 < 16) STAGE(t + 3);
    const unsigned short* bufp = smem + (t & 3) * 10240;
    const unsigned short* sa = bufp + (wm * 64 + lr) * 32 + gx;
    const unsigned short* sb = bufp + 4096 + (wn * 48 + lr) * 32 + gx;
    f16x8 a0 = *(const f16x8*)(sa);
    f16x8 a1 = *(const f16x8*)(sa + 512);
    f16x8 a2 = *(const f16x8*)(sa + 1024);
    f16x8 a3 = *(const f16x8*)(sa + 1536);
    f16x8 b0 = *(const f16x8*)(sb);
    f16x8 b1 = *(const f16x8*)(sb + 512);
    f16x8 b2 = *(const f16x8*)(sb + 1024);
    acc[0][0] = mfma16(a0, b0, acc[0][0]);
    acc[0][1] = mfma16(a0, b1, acc[0][1]);
    acc[0][2] = mfma16(a0, b2, acc[0][2]);
    acc[1][0] = mfma16(a1, b0, acc[1][0]);
    acc[1][1] = mfma16(a1, b1, acc[1][1]);
    acc[1][2] = mfma16(a1, b2, acc[1][2]);
    acc[2][0] = mfma16(a2, b0, acc[2][0]);
    acc[2][1] = mfma16(a2, b1, acc[2][1]);
    acc[2][2] = mfma16(a2, b2, acc[2][2]);
    acc[3][0] = mfma16(a3, b0, acc[3][0]);
    acc[3][1] = mfma16(a3, b1, acc[3][1]);
    acc[3][2] = mfma16(a3, b2, acc[3][2]);
    // counted wait: tile t+1 must be resident at the barrier
    if (t < 13) {
      if (cw3) { VMCNT(6); } else { VMCNT(4); }
    } else if (t == 13) {
      if (cw3) { VMCNT(3); } else { VMCNT(2); }
    } else if (t == 14) {
      VMCNT(0);
    }
    __builtin_amdgcn_s_barrier();
  }

  // ---- epilogue overlay ----
  unsigned short* SQ = smem;                 // [128][136] q|k
  unsigned short* VT = smem + 17408;         // [7(8)][64][24] v^T (tl 0..16)
  unsigned short* PL = smem + 29696;         // [8][16][24] P f16
  float* SE = (float*)(smem + 32768);        // [8][34] edge logits

  // epi-1: acc(+bias) -> scratch
  {
    const int er0 = wm * 64 + (lane >> 4) * 4;
    const int ec0 = wn * 48 + lr;
#pragma unroll
    for (int nf = 0; nf < 3; ++nf) {
      const int col = ec0 + nf * 16;
      const float bv = bqp[bcol + col];
#pragma unroll
      for (int mf = 0; mf < 4; ++mf) {
        const int t0 = er0 + mf * 16;
        float v0 = acc[mf][nf][0] + bv, v1 = acc[mf][nf][1] + bv;
        float v2 = acc[mf][nf][2] + bv, v3 = acc[mf][nf][3] + bv;
        if (col < 128) {
          SQ[(t0 + 0) * 136 + col] = f2h(v0);
          SQ[(t0 + 1) * 136 + col] = f2h(v1);
          SQ[(t0 + 2) * 136 + col] = f2h(v2);
          SQ[(t0 + 3) * 136 + col] = f2h(v3);
        } else {
          const int d = col - 128;
#pragma unroll
          for (int rr = 0; rr < 4; ++rr) {
            const int tt = t0 + rr;
            const int bb = tt / 17, tl = tt - bb * 17;
            float vv = (rr == 0 ? v0 : rr == 1 ? v1 : rr == 2 ? v2 : v3);
            if (bb < 7) VT[bb * 1536 + d * 24 + tl] = f2h(vv);
          }
        }
      }
    }
  }
  __syncthreads();

  // epi-2: per-wave MFMA attention, batch = w
  const int nb = min(7, 8192 - batch0);
  if (w < nb) {
    const float alpha = alpha_p[0];
    const int base = w * 17;
    unsigned short* PLw = PL + w * 384;
    unsigned short* VTw = VT + w * 1536;
    float* SEw = SE + w * 34;

    // logits main 16x16, K=64 via 2 MFMA (A=q rows, B=k rows -> q.k^T)
    f32x4 sAcc = f32x4{0.f, 0.f, 0.f, 0.f};
#pragma unroll
    for (int kk = 0; kk < 2; ++kk) {
      f16x8 qa = *(const f16x8*)(SQ + (base + lr) * 136 + kk * 32 + lk * 8);
      f16x8 kb = *(const f16x8*)(SQ + (base + lr) * 136 + 64 + kk * 32 + lk * 8);
      sAcc = mfma16(qa, kb, sAcc);
    }

    // edge dots: lanes 0..15 -> (r,16); lanes 16..32 -> (16,m)
    if (lane < 33) {
      const int r_ = (lane < 16) ? lane : 16;
      const int m_ = (lane < 16) ? 16 : lane - 16;
      const uint4* qr = (const uint4*)(SQ + (base + r_) * 136);
      const uint4* kr = (const uint4*)(SQ + (base + m_) * 136 + 64);
      float dt = 0.f;
#pragma unroll
      for (int c = 0; c < 8; ++c) {
        uint4 qa = qr[c], ka = kr[c];
        dt = fdot2u(qa.x, ka.x, dt);
        dt = fdot2u(qa.y, ka.y, dt);
        dt = fdot2u(qa.z, ka.z, dt);
        dt = fdot2u(qa.w, ka.w, dt);
      }
      float sv = (dt + alpha * outer[h * 289 + r_ * 17 + m_]) * 0.125f;
      SEw[(lane < 16) ? lane : (17 + m_)] = sv;
    }
    __builtin_amdgcn_wave_barrier();
    asm volatile("" ::: "memory");

    // softmax on C-layout: col=m=lr, rows g4+j
    const int g4 = (lane >> 4) * 4;
    float sp[4], rmax[4], p[4], pe[4], rsum[4], inv[4];
#pragma unroll
    for (int j = 0; j < 4; ++j) {
      sp[j] = (sAcc[j] + alpha * outer[h * 289 + (g4 + j) * 17 + lr]) * 0.125f;
      rmax[j] = sp[j];
    }
#pragma unroll
    for (int d = 1; d < 16; d <<= 1)
#pragma unroll
      for (int j = 0; j < 4; ++j)
        rmax[j] = fmaxf(rmax[j], __shfl_xor(rmax[j], d));
#pragma unroll
    for (int j = 0; j < 4; ++j) {
      float ec = SEw[g4 + j];           // S[row][16]
      rmax[j] = fmaxf(rmax[j], ec);
      p[j] = __expf(sp[j] - rmax[j]);
      pe[j] = __expf(ec - rmax[j]);
      rsum[j] = p[j];
    }
#pragma unroll
    for (int d = 1; d < 16; d <<= 1)
#pragma unroll
      for (int j = 0; j < 4; ++j) rsum[j] += __shfl_xor(rsum[j], d);
#pragma unroll
    for (int j = 0; j < 4; ++j) {
      rsum[j] += pe[j];
      inv[j] = 1.f / rsum[j];
      PLw[(g4 + j) * 24 + lr] = f2h(p[j]);
    }
    __builtin_amdgcn_wave_barrier();
    asm volatile("" ::: "memory");

    // PV: 4x mfma 16x16x16 (tokens 0..15) + in-register rank-1 for token 16
    f16x4 pa = *(const f16x4*)(PLw + lr * 24 + lk * 4);
    f32x4 o[4];
    float v16[4];
#pragma unroll
    for (int nf = 0; nf < 4; ++nf) {
      f16x4 vb = *(const f16x4*)(VTw + (nf * 16 + lr) * 24 + lk * 4);
      o[nf] = mfma16k16(pa, vb, f32x4{0.f, 0.f, 0.f, 0.f});
      v16[nf] = h2f(VTw[(nf * 16 + lr) * 24 + 16]);
    }
    const size_t gr0 = (size_t)(brow + base) * 512 + h * 64;
#pragma unroll
    for (int nf = 0; nf < 4; ++nf)
#pragma unroll
      for (int j = 0; j < 4; ++j)
        ao[gr0 + (size_t)(g4 + j) * 512 + nf * 16 + lr] =
            f2h((o[nf][j] + pe[j] * v16[nf]) * inv[j]);

    // row 16: VALU (lane = d)
    {
      float mx16 = -1e30f;
#pragma unroll 1
      for (int m = 0; m < 17; ++m) mx16 = fmaxf(mx16, SEw[17 + m]);
      float o16 = 0.f, s16 = 0.f;
#pragma unroll 1
      for (int m = 0; m < 17; ++m) {
        float pm = __expf(SEw[17 + m] - mx16);
        s16 += pm;
        o16 += pm * h2f(VTw[lane * 24 + m]);
      }
      ao[gr0 + (size_t)16 * 512 + lane] = f2h(o16 / s16);
    }
  }
}

// ============ proj GEMM: 128x128, BK=32, 4 buffers, counted vmcnt ========
__global__ __launch_bounds__(512, 4) void k_proj(
    const unsigned short* __restrict__ A,   // ao [139264][512] f16
    const unsigned short* __restrict__ Bt,  // wpt [512][512] f16
    const float* __restrict__ bias,         // [512]
    float* __restrict__ C) {                // [139264][512] fp32
  __shared__ __align__(16) unsigned short smem[32768];  // 65,536 B

  const int tid = threadIdx.x;
  const int w = tid >> 6, lane = tid & 63;
  const int wm = w >> 2, wn = w & 3;
  const int lr = lane & 15, lk = lane >> 4;

  const int bid = (blockIdx.x & 7) * ((int)gridDim.x >> 3) + (blockIdx.x >> 3);
  const int brow = (bid >> 2) << 7;
  const int bcol = (bid & 3) << 7;

  const int rsl = lane >> 2;
  const int swcol = ((lane & 3) ^ ((lane >> 3) & 3)) << 3;

  f32x4 acc[4][2];
#pragma unroll
  for (int m = 0; m < 4; m++)
#pragma unroll
    for (int n = 0; n < 2; n++) acc[m][n] = f32x4{0.f, 0.f, 0.f, 0.f};

  auto STAGE1 = [&](int t, int s) {
    unsigned short* dst = smem + (t & 3) * 8192 + s * 512;
    const unsigned short* src =
        (s < 8) ? A + (size_t)(brow + s * 16 + rsl) * 512 + t * 32 + swcol
                : Bt + (size_t)(bcol + (s - 8) * 16 + rsl) * 512 + t * 32 + swcol;
    GLOAD_LDS16(src, dst);
  };
  auto STAGE = [&](int t) {
    STAGE1(t, w);
    STAGE1(t, w + 8);
  };

  STAGE(0); STAGE(1); STAGE(2);
  VMCNT(4);
  __builtin_amdgcn_s_barrier();

  const int gx = (lk ^ ((lr >> 1) & 3)) << 3;
  for (int t = 0; t < 16; ++t) {
    if (t + 3 < 16) STAGE(t + 3);
    const unsigned short* bufp = smem + (t & 3) * 8192;
    const unsigned short* sa = bufp + (wm * 64 + lr) * 32 + gx;
    const unsigned short* sb = bufp + 4096 + (wn * 32 + lr) * 32 + gx;
    f16x8 a0 = *(const f16x8*)(sa);
    f16x8 a1 = *(const f16x8*)(sa + 512);
    f16x8 a2 = *(const f16x8*)(sa + 1024);
    f16x8 a3 = *(const f16x8*)(sa + 1536);
    f16x8 b0 = *(const f16x8*)(sb);
    f16x8 b1 = *(const f16x8*)(sb + 512);
    acc[0][0] = mfma16(a0, b0, acc[0][0]);
    acc[0][1] = mfma16(a0, b1, acc[0][1]);
    acc[1][0] = mfma16(a1, b0, acc[1][0]);
    acc[1][1] = mfma16(a1, b1, acc[1][1]);
    acc[2][0] = mfma16(a2, b0, acc[2][0]);
    acc[2][1] = mfma16(a2, b1, acc[2][1]);
    acc[3][0] = mfma16(a3, b0, acc[3][0]);
    acc[3][1] = mfma16(a3, b1, acc[3][1]);
    if (t < 13) {
      VMCNT(4);
    } else if (t == 13) {
      VMCNT(2);
    } else if (t == 14) {
      VMCNT(0);
    }
    __builtin_amdgcn_s_barrier();
  }

  const int orow = brow + wm * 64 + (lane >> 4) * 4;
  const int ocol0 = bcol + wn * 32 + lr;
#pragma unroll
  for (int n = 0; n < 2; n++) {
    const int col = ocol0 + n * 16;
    const float bv = bias[col];
#pragma unroll
    for (int m = 0; m < 4; m++) {
      const int row = orow + m * 16;
#pragma unroll
      for (int r = 0; r < 4; r++)
        C[(size_t)(row + r) * 512 + col] = acc[m][n][r] + bv;
    }
  }
}

// ---------------- launch ----------------
extern "C" void kernel_launch(void* const* d_in, const int* in_sizes, int n_in,
                              void* d_out, int out_size, void* d_ws,
                              size_t ws_size, hipStream_t stream) {
  const float* x      = (const float*)d_in[0];
  const float* W_qkv  = (const float*)d_in[1];
  const float* b_qkv  = (const float*)d_in[2];
  const float* outer  = (const float*)d_in[3];
  const float* alpha  = (const float*)d_in[4];
  const float* W_proj = (const float*)d_in[5];
  const float* b_proj = (const float*)d_in[6];

  char* ws = (char*)d_ws;
  unsigned short* xb  = (unsigned short*)(ws);              // 142,606,336 B
  unsigned short* ao  = (unsigned short*)(ws + 142606336);  // 142,606,336 B
  unsigned short* wqt = (unsigned short*)(ws + 285212672);  // 1,572,864 B
  unsigned short* wpt = (unsigned short*)(ws + 286785536);  // 524,288 B
  float*          bqp = (float*)(ws + 287309824);           // 6,144 B

  k_cvt<<<dim3(69632), dim3(256), 0, stream>>>(x, xb, 17825792L);
  k_cvt_t<true><<<dim3(3072), dim3(256), 0, stream>>>(W_qkv, wqt, 512, 1536);
  k_cvt_t<false><<<dim3(1024), dim3(256), 0, stream>>>(W_proj, wpt, 512, 512);
  k_permb<<<dim3(6), dim3(256), 0, stream>>>(b_qkv, bqp);

  // fused qkv-GEMM + attention: 1171 row-tiles (7 batches each) x 8 heads
  k_fused<<<dim3(9368), dim3(512), 0, stream>>>(xb, wqt, bqp, outer, alpha, ao);

  // proj GEMM: 1088 row-tiles x 4 col-tiles
  k_proj<<<dim3(4352), dim3(512), 0, stream>>>(ao, wpt, b_proj, (float*)d_out);
}